// Round 9
// baseline (538.110 us; speedup 1.0000x reference)
//
#include <hip/hip_runtime.h>
#include <stdint.h>

#define D_IN 512
#define D_HID 256

typedef __attribute__((ext_vector_type(8))) short bf16x8;
typedef __attribute__((ext_vector_type(8))) unsigned short u16x8;
typedef __attribute__((ext_vector_type(4))) float f32x4;

__device__ __forceinline__ float b2f(unsigned short u) {
    union { float f; uint32_t i; } x; x.i = ((uint32_t)u) << 16; return x.f;
}
__device__ __forceinline__ unsigned short f2b(float f) {
    union { float f; uint32_t i; } x; x.f = f;
    uint32_t i = x.i;
    uint32_t r = (i + 0x7FFFu + ((i >> 16) & 1u)) >> 16;
    return (unsigned short)r;
}

// async global->LDS 16B copy; dest is wave-uniform base + lane*16 (HW rule)
__device__ __forceinline__ void async_copy16(const unsigned short* g, unsigned short* lds) {
    __builtin_amdgcn_global_load_lds((const __attribute__((address_space(1))) unsigned int*)g,
                                     (__attribute__((address_space(3))) unsigned int*)lds,
                                     16, 0, 0);
}

// ---------- dtype detector (parallel): flag|=1 if raw bits are float32 ----------
__global__ __launch_bounds__(256) void detect_dtype_kernel(const ushort4* __restrict__ raw,
                                                           int n4, int* __restrict__ flag) {
    int i = blockIdx.x * blockDim.x + threadIdx.x;
    int hit = 0;
    if (i < n4) {
        ushort4 u = raw[i];
        hit = ((((u.x >> 7) & 0xFF) == 0xFF) || (((u.y >> 7) & 0xFF) == 0xFF) ||
               (((u.z >> 7) & 0xFF) == 0xFF) || (((u.w >> 7) & 0xFF) == 0xFF)) ? 1 : 0;
    }
    unsigned long long b = __ballot(hit);
    if ((threadIdx.x & 63) == 0 && b != 0ULL) atomicOr(flag, 1);
}

// ---------- W pack body: fragment order ----------
//   Wp[(((kk*2 + h)*16 + c)*64 + lane)*8 + j] = W[kk*64 + h*32 + (lane>>4)*8 + j][c*16 + (lane&15)]
// One wave B-fragment load = 1 KB contiguous (validated r6).
__device__ __forceinline__ void wpack_body(const void* __restrict__ W,
        unsigned short* __restrict__ Wp, int K, bool f32, int t) {
    int total = (K >> 6) * 2 * 16 * 64;
    if (t >= total) return;
    int lane = t & 63;
    int c = (t >> 6) & 15;
    int h = (t >> 10) & 1;
    int kk = t >> 11;
    int n = c * 16 + (lane & 15);
    int k0 = kk * 64 + h * 32 + (lane >> 4) * 8;
    u16x8 o;
#pragma unroll
    for (int j = 0; j < 8; ++j) {
        float v = f32 ? ((const float*)W)[(size_t)(k0 + j) * 256 + n]
                      : b2f(((const unsigned short*)W)[(size_t)(k0 + j) * 256 + n]);
        o[j] = f2b(v);
    }
    *(u16x8*)(Wp + (size_t)t * 8) = o;
}

// ---------- fused independent pre-work: hist (long pole) + wpack1 + wpack2 ----------
__global__ __launch_bounds__(256) void pre_fused_kernel(const int* __restrict__ dst,
        int* __restrict__ counts, int E,
        const void* __restrict__ W1, unsigned short* __restrict__ Wp1,
        const void* __restrict__ W2, unsigned short* __restrict__ Wp2,
        const int* __restrict__ flag, int histBlocks, int wp1Blocks) {
    int b = blockIdx.x;
    if (b < histBlocks) {
        int e = b * 256 + threadIdx.x;
        if (e < E) atomicAdd(&counts[dst[e]], 1);
        return;
    }
    b -= histBlocks;
    bool f32 = (*flag != 0);
    if (b < wp1Blocks) {
        wpack_body(W1, Wp1, D_IN, f32, b * 256 + threadIdx.x);
    } else {
        wpack_body(W2, Wp2, D_HID, f32, (b - wp1Blocks) * 256 + threadIdx.x);
    }
}

// ---------- parallel scan P1/P2/P3 ----------
__global__ __launch_bounds__(256) void partial_sum_kernel(const int* __restrict__ counts,
        int* __restrict__ partial, int n) {
    __shared__ int sh[4];
    int b = blockIdx.x;
    int lane = threadIdx.x & 63, wv = threadIdx.x >> 6;
    int s = 0;
    for (int j = threadIdx.x; j < 1024; j += 256) {
        int i = b * 1024 + j;
        s += (i < n) ? counts[i] : 0;
    }
#pragma unroll
    for (int off = 32; off > 0; off >>= 1) s += __shfl_down(s, off, 64);
    if (lane == 0) sh[wv] = s;
    __syncthreads();
    if (threadIdx.x == 0) partial[b] = sh[0] + sh[1] + sh[2] + sh[3];
}

__global__ void scan_partials_kernel(int* __restrict__ partial, int nb,
                                     int* __restrict__ indptr, int N) {
    int lane = threadIdx.x & 63;
    int orig = (lane < nb) ? partial[lane] : 0;
    int v = orig;
#pragma unroll
    for (int off = 1; off < 64; off <<= 1) {
        int u = __shfl(v, lane - off, 64);
        if (lane >= off) v += u;
    }
    int tot = __shfl(v, nb - 1, 64);
    if (lane < nb) partial[lane] = v - orig;
    if (lane == 0) indptr[N] = tot;
}

__global__ __launch_bounds__(1024) void scan_chunk_kernel(const int* __restrict__ counts,
        const int* __restrict__ partial, int* __restrict__ indptr, int* __restrict__ cursor,
        float* __restrict__ dinv, int n) {
    __shared__ int sh[1024];
    int b = blockIdx.x;
    int i = b * 1024 + threadIdx.x;
    int v = (i < n) ? counts[i] : 0;
    sh[threadIdx.x] = v;
    __syncthreads();
    for (int off = 1; off < 1024; off <<= 1) {
        int t = (threadIdx.x >= off) ? sh[threadIdx.x - off] : 0;
        __syncthreads();
        sh[threadIdx.x] += t;
        __syncthreads();
    }
    if (i < n) {
        int e = partial[b] + sh[threadIdx.x] - v;
        indptr[i] = e;
        cursor[i] = e;
        dinv[i] = rsqrtf((float)(v + 1));
    }
}

// ---------- MFMA GEMM: C[M,256] = A[M,K] @ W[K,256], fused (FUSE) with:
//   tail range 1: CSR scatter (atomic; writes csr_src scattered + pos_of coalesced;
//                 csr_dst is NOT written here -- r8 showed scattered 4B streams cost
//                 8x cross-XCD write amplification)
//   tail range 2: csr_dst run-fill from indptr (coalesced-ish)
// gemm blocks FIRST so BW-bound work starts immediately; latency-bound scatter
// fills the remaining slots.
// gemm: 256 thr / 4 waves; tile 64 rows x 256 cols; BK=64, double-buffered A via
// async_copy16 (bf16) or reg-staged f32->bf16 (MF32 && *flag). B from fragment-
// packed Wp (8 x 1KB coalesced/step). LDS: 128B rows, seg rotation (seg+row)&7.
template<int K, bool MF32, bool FUSE>
__global__ __launch_bounds__(256) void gemm_bf16(const void* __restrict__ Ain,
        const unsigned short* __restrict__ Wp, unsigned short* __restrict__ C, int M,
        const int* __restrict__ flag,
        const int* __restrict__ eidx, int* __restrict__ cursor, int* __restrict__ csr_src,
        int* __restrict__ csr_dst, int* __restrict__ pos_of,
        const int* __restrict__ indptr, int E, int sblocks) {
    __shared__ unsigned short As[2][64 * 64];    // 2 x 8 KB
    constexpr int NK = K / 64;
    int bid = blockIdx.x;
    int gblocks = (M + 63) >> 6;
    if (FUSE) {
        if (bid >= gblocks) {
            int tb = bid - gblocks;
            if (tb < sblocks) {
                int e = tb * 256 + (int)threadIdx.x;
                if (e < E) {
                    int d = eidx[(size_t)E + e];
                    int pos = atomicAdd(&cursor[d], 1);
                    csr_src[pos] = eidx[e];
                    pos_of[e] = pos;
                }
            } else {
                int v = (tb - sblocks) * 256 + (int)threadIdx.x;
                if (v < M) {
                    int b0 = indptr[v], e0 = indptr[v + 1];
                    for (int p = b0; p < e0; ++p) csr_dst[p] = v;
                }
            }
            return;
        }
    }
    int t = threadIdx.x;
    int lane = t & 63, wv = t >> 6;
    int n0 = lane & 15, grp = lane >> 4;
    int row0 = bid * 64;

    int srow = wv * 16 + (lane >> 3);         // + j*8 added per issue
    int segp = lane & 7;

    f32x4 acc[4][4];
#pragma unroll
    for (int rt = 0; rt < 4; ++rt)
#pragma unroll
        for (int ct = 0; ct < 4; ++ct) acc[rt][ct] = (f32x4){0.f, 0.f, 0.f, 0.f};

    auto compute_tile = [&](int kk, const unsigned short* Abuf) {
        bf16x8 bw[4][2];
#pragma unroll
        for (int ct = 0; ct < 4; ++ct)
#pragma unroll
            for (int h = 0; h < 2; ++h)
                bw[ct][h] = *(const bf16x8*)(Wp +
                    ((size_t)(((kk * 2 + h) * 16) + (wv * 4 + ct)) * 64 + lane) * 8);
#pragma unroll
        for (int rt = 0; rt < 4; ++rt) {
            int r = rt * 16 + n0;
#pragma unroll
            for (int h = 0; h < 2; ++h) {
                int sp = (h * 4 + grp + r) & 7;
                bf16x8 a = *(const bf16x8*)(Abuf + r * 64 + sp * 8);
#pragma unroll
                for (int ct = 0; ct < 4; ++ct)
                    acc[rt][ct] = __builtin_amdgcn_mfma_f32_16x16x32_bf16(a, bw[ct][h],
                                                                          acc[rt][ct], 0, 0, 0);
            }
        }
    };

    bool f32src = MF32 && (*flag != 0);
    if (f32src) {
        const float* A = (const float*)Ain;
        auto stage_f32 = [&](int buf, const float4* pr) {
#pragma unroll
            for (int j = 0; j < 2; ++j) {
                u16x8 o;
#pragma unroll
                for (int q = 0; q < 4; ++q) {
                    o[q]     = f2b(pr[j * 2 + 0][q]);
                    o[q + 4] = f2b(pr[j * 2 + 1][q]);
                }
                *(u16x8*)(&As[buf][0] + wv * 1024 + j * 512 + lane * 8) = o;
            }
        };
        auto load_f32 = [&](int kof, float4* pr) {
#pragma unroll
            for (int j = 0; j < 2; ++j) {
                int row = srow + j * 8;
                int s = (segp - row) & 7;
                const float* g = A + (size_t)min(row0 + row, M - 1) * K + kof + s * 8;
                pr[j * 2 + 0] = *(const float4*)(g);
                pr[j * 2 + 1] = *(const float4*)(g + 4);
            }
        };
        float4 pr[4];
        load_f32(0, pr);
        stage_f32(0, pr);
        for (int kk = 0; kk < NK; ++kk) {
            int cur = kk & 1;
            if (kk + 1 < NK) load_f32((kk + 1) * 64, pr);   // in flight across compute
            asm volatile("s_waitcnt lgkmcnt(0)" ::: "memory");  // my ds_writes done
            __builtin_amdgcn_s_barrier();                       // buf[cur] visible to all
            compute_tile(kk, &As[cur][0]);
            if (kk + 1 < NK) stage_f32(cur ^ 1, pr);
        }
    } else {
        const unsigned short* A = (const unsigned short*)Ain;
#pragma unroll
        for (int j = 0; j < 2; ++j) {
            int row = srow + j * 8;
            int s = (segp - row) & 7;
            const unsigned short* g = A + (size_t)min(row0 + row, M - 1) * K + s * 8;
            async_copy16(g, &As[0][0] + wv * 1024 + j * 512);
        }
        asm volatile("s_waitcnt vmcnt(0)" ::: "memory");
        __builtin_amdgcn_s_barrier();
        for (int kk = 0; kk < NK; ++kk) {
            int cur = kk & 1;
            if (kk + 1 < NK) {
                int kof = (kk + 1) * 64;
#pragma unroll
                for (int j = 0; j < 2; ++j) {
                    int row = srow + j * 8;
                    int s = (segp - row) & 7;
                    const unsigned short* g = A + (size_t)min(row0 + row, M - 1) * K + kof + s * 8;
                    async_copy16(g, &As[cur ^ 1][0] + wv * 1024 + j * 512);
                }
            }
            compute_tile(kk, &As[cur][0]);
            asm volatile("s_waitcnt vmcnt(0)" ::: "memory");
            __builtin_amdgcn_s_barrier();
        }
    }
#pragma unroll
    for (int rt = 0; rt < 4; ++rt) {
#pragma unroll
        for (int ct = 0; ct < 4; ++ct) {
#pragma unroll
            for (int reg = 0; reg < 4; ++reg) {
                int row = row0 + rt * 16 + grp * 4 + reg;
                if (row < M)
                    C[(size_t)row * 256 + (wv * 4 + ct) * 16 + n0] = f2b(acc[rt][ct][reg]);
            }
        }
    }
}

// ---------- FUSED aggregate(layer1: +b, relu) @ W2: hA -> C (skips h1 buffer) ----------
// Block = 256 thr / 4 waves; tile = 64 nodes. Each wave aggregates 16 nodes with the
// validated 2-half x 3-deep gather pipeline, writes bf16 rows DIRECTLY into the
// seg-rotated LDS A-layout (bit-identical to the old hB->DMA path: f2b at write),
// one barrier, then the validated Wp compute loop (K=256, NK=4) + C epilogue.
// Deletes the 51 MB h1 round-trip; MFMA+W reads hide under gather latency.
__global__ __launch_bounds__(256) void agg_gemm_kernel(const unsigned short* __restrict__ h,
        const int* __restrict__ indptr, const int* __restrict__ csr_src,
        const float* __restrict__ dinv, const void* __restrict__ bias,
        const unsigned short* __restrict__ Wp, unsigned short* __restrict__ C,
        int n, const int* __restrict__ flag) {
    __shared__ unsigned short T[4][64 * 64];   // 32 KB: 4 K-slices, seg-rotated
    int t = threadIdx.x;
    int lane = t & 63, wv = t >> 6;
    int half = lane >> 5, hl = lane & 31;
    int row0 = blockIdx.x * 64;

    float bb[8];
    if (*flag != 0) {
        const float* bp = (const float*)bias + hl * 8;
#pragma unroll
        for (int i = 0; i < 8; ++i) bb[i] = bp[i];
    } else {
        const unsigned short* bp = (const unsigned short*)bias + hl * 8;
#pragma unroll
        for (int i = 0; i < 8; ++i) bb[i] = b2f(bp[i]);
    }

    for (int i = 0; i < 16; ++i) {
        int r = wv * 16 + i;
        int v = row0 + r;
        int kk = hl >> 3, s = hl & 7, sp = (s + r) & 7;
        if (v < n) {
            int beg = indptr[v];
            int end = indptr[v + 1];
            float dv = dinv[v];
            float acc[8];
            if (half == 0) {
                u16x8 hv = *(const u16x8*)(h + (size_t)v * 256 + hl * 8);
#pragma unroll
                for (int j = 0; j < 8; ++j) acc[j] = dv * b2f(hv[j]);
            } else {
#pragma unroll
                for (int j = 0; j < 8; ++j) acc[j] = 0.f;
            }
            float wA = 0.f, wB = 0.f, wC = 0.f;
            u16x8 rA = (u16x8)0, rB = (u16x8)0, rC = (u16x8)0;
            auto ld = [&](int idx, float& w, u16x8& r2) {
                if (idx < end) {
                    int s2 = csr_src[idx];
                    w = dinv[s2];
                    r2 = *(const u16x8*)(h + (size_t)s2 * 256 + hl * 8);
                } else {
                    w = 0.f;
                }
            };
            int e = beg + half;
            ld(e, wA, rA);
            ld(e + 2, wB, rB);
            ld(e + 4, wC, rC);
            while (e + 4 < end) {
#pragma unroll
                for (int j = 0; j < 8; ++j) acc[j] += wA * b2f(rA[j]);
                ld(e + 6, wA, rA);
#pragma unroll
                for (int j = 0; j < 8; ++j) acc[j] += wB * b2f(rB[j]);
                ld(e + 8, wB, rB);
#pragma unroll
                for (int j = 0; j < 8; ++j) acc[j] += wC * b2f(rC[j]);
                ld(e + 10, wC, rC);
                e += 6;
            }
#pragma unroll
            for (int j = 0; j < 8; ++j)
                acc[j] += wA * b2f(rA[j]) + wB * b2f(rB[j]) + wC * b2f(rC[j]);
#pragma unroll
            for (int j = 0; j < 8; ++j) acc[j] += __shfl_xor(acc[j], 32, 64);
            if (half == 0) {
                u16x8 o;
#pragma unroll
                for (int j = 0; j < 8; ++j) {
                    float ov = fmaxf(dv * acc[j] + bb[j], 0.f);   // layer-1 relu
                    o[j] = f2b(ov);
                }
                *(u16x8*)(&T[kk][0] + r * 64 + sp * 8) = o;
            }
        } else if (half == 0) {
            *(u16x8*)(&T[kk][0] + r * 64 + sp * 8) = (u16x8)0;
        }
    }
    __syncthreads();

    int n0 = lane & 15, grp = lane >> 4;
    f32x4 acc2[4][4];
#pragma unroll
    for (int rt = 0; rt < 4; ++rt)
#pragma unroll
        for (int ct = 0; ct < 4; ++ct) acc2[rt][ct] = (f32x4){0.f, 0.f, 0.f, 0.f};
#pragma unroll
    for (int kk = 0; kk < 4; ++kk) {
        bf16x8 bw[4][2];
#pragma unroll
        for (int ct = 0; ct < 4; ++ct)
#pragma unroll
            for (int h2 = 0; h2 < 2; ++h2)
                bw[ct][h2] = *(const bf16x8*)(Wp +
                    ((size_t)(((kk * 2 + h2) * 16) + (wv * 4 + ct)) * 64 + lane) * 8);
#pragma unroll
        for (int rt = 0; rt < 4; ++rt) {
            int r = rt * 16 + n0;
#pragma unroll
            for (int h2 = 0; h2 < 2; ++h2) {
                int sp = (h2 * 4 + grp + r) & 7;
                bf16x8 a = *(const bf16x8*)(&T[kk][0] + r * 64 + sp * 8);
#pragma unroll
                for (int ct = 0; ct < 4; ++ct)
                    acc2[rt][ct] = __builtin_amdgcn_mfma_f32_16x16x32_bf16(a, bw[ct][h2],
                                                                           acc2[rt][ct], 0, 0, 0);
            }
        }
    }
#pragma unroll
    for (int rt = 0; rt < 4; ++rt) {
#pragma unroll
        for (int ct = 0; ct < 4; ++ct) {
#pragma unroll
            for (int reg = 0; reg < 4; ++reg) {
                int row = row0 + rt * 16 + grp * 4 + reg;
                if (row < n)
                    C[(size_t)row * 256 + (wv * 4 + ct) * 16 + n0] = f2b(acc2[rt][ct][reg]);
            }
        }
    }
}

// ---------- GCN aggregation (bf16 h in, bf16 out, f32 accum) -- layer 2 ----------
// Two 32-lane halves x mov-free 3-stage rotation; at the gather request-rate ceiling.
__global__ __launch_bounds__(256) void aggregate_kernel(const unsigned short* __restrict__ h,
        const int* __restrict__ indptr, const int* __restrict__ csr_src,
        const float* __restrict__ dinv, const void* __restrict__ bias,
        unsigned short* __restrict__ out, int n, int do_relu, const int* __restrict__ flag) {
    int wave = threadIdx.x >> 6;
    int lane = threadIdx.x & 63;
    int half = lane >> 5;
    int hl = lane & 31;
    int v = blockIdx.x * 4 + wave;
    if (v >= n) return;
    int beg = indptr[v];
    int end = indptr[v + 1];
    float dv = dinv[v];

    float acc[8];
    if (half == 0) {
        u16x8 hv = *(const u16x8*)(h + (size_t)v * 256 + hl * 8);
#pragma unroll
        for (int i = 0; i < 8; ++i) acc[i] = dv * b2f(hv[i]);
    } else {
#pragma unroll
        for (int i = 0; i < 8; ++i) acc[i] = 0.f;
    }

    float wA = 0.f, wB = 0.f, wC = 0.f;
    u16x8 rA = (u16x8)0, rB = (u16x8)0, rC = (u16x8)0;
    auto ld = [&](int idx, float& w, u16x8& r) {
        if (idx < end) {
            int s = csr_src[idx];
            w = dinv[s];
            r = *(const u16x8*)(h + (size_t)s * 256 + hl * 8);
        } else {
            w = 0.f;
        }
    };
    int e = beg + half;
    ld(e, wA, rA);
    ld(e + 2, wB, rB);
    ld(e + 4, wC, rC);
    while (e + 4 < end) {
#pragma unroll
        for (int i = 0; i < 8; ++i) acc[i] += wA * b2f(rA[i]);
        ld(e + 6, wA, rA);
#pragma unroll
        for (int i = 0; i < 8; ++i) acc[i] += wB * b2f(rB[i]);
        ld(e + 8, wB, rB);
#pragma unroll
        for (int i = 0; i < 8; ++i) acc[i] += wC * b2f(rC[i]);
        ld(e + 10, wC, rC);
        e += 6;
    }
#pragma unroll
    for (int i = 0; i < 8; ++i)
        acc[i] += wA * b2f(rA[i]) + wB * b2f(rB[i]) + wC * b2f(rC[i]);

#pragma unroll
    for (int i = 0; i < 8; ++i) acc[i] += __shfl_xor(acc[i], 32, 64);

    if (half == 0) {
        float bb[8];
        if (*flag != 0) {
            const float* bp = (const float*)bias + hl * 8;
#pragma unroll
            for (int i = 0; i < 8; ++i) bb[i] = bp[i];
        } else {
            const unsigned short* bp = (const unsigned short*)bias + hl * 8;
#pragma unroll
            for (int i = 0; i < 8; ++i) bb[i] = b2f(bp[i]);
        }
        u16x8 ov;
#pragma unroll
        for (int i = 0; i < 8; ++i) {
            float o = dv * acc[i] + bb[i];
            if (do_relu) o = fmaxf(o, 0.f);
            ov[i] = f2b(o);
        }
        *(u16x8*)(out + (size_t)v * 256 + hl * 8) = ov;
    }
}

// ---------- edge scoring via MFMA: 16 CSR-ordered edges per wave ----------
__global__ __launch_bounds__(256) void edge_score_mfma(const unsigned short* __restrict__ h,
        const int* __restrict__ csr_src, const int* __restrict__ csr_dst,
        float* __restrict__ tmp, int E) {
    int lane = threadIdx.x & 63;
    int wv = threadIdx.x >> 6;
    int base = (blockIdx.x * 4 + wv) * 16;
    if (base >= E) return;
    int m = lane & 15, grp = lane >> 4;
    int e = base + m;
    int ec = min(e, E - 1);
    int s = csr_src[ec], d = csr_dst[ec];
    const unsigned short* hs = h + (size_t)s * 256 + grp * 8;
    const unsigned short* hd = h + (size_t)d * 256 + grp * 8;
    f32x4 acc = {0.f, 0.f, 0.f, 0.f};
#pragma unroll
    for (int kk = 0; kk < 8; ++kk) {
        bf16x8 a = *(const bf16x8*)(hs + kk * 32);
        bf16x8 b = *(const bf16x8*)(hd + kk * 32);
        acc = __builtin_amdgcn_mfma_f32_16x16x32_bf16(a, b, acc, 0, 0, 0);
    }
    int reg = m - grp * 4;
    if (reg >= 0 && reg < 4 && e < E) {
        float p = (reg == 0) ? acc[0] : (reg == 1) ? acc[1] : (reg == 2) ? acc[2] : acc[3];
        tmp[e] = 1.f / (1.f + __expf(-p));   // CSR-slot order: coalesced
    }
}

// out[e] = tmp[pos_of[e]] -- L2/L3-resident gather + sequential write.
__global__ __launch_bounds__(256) void permute_out_kernel(const float* __restrict__ tmp,
        const int* __restrict__ pos_of, void* __restrict__ out, int E,
        const int* __restrict__ flag) {
    int e = blockIdx.x * blockDim.x + threadIdx.x;
    if (e >= E) return;
    float p = tmp[pos_of[e]];
    if (*flag != 0)
        ((float*)out)[e] = p;
    else
        ((unsigned short*)out)[e] = f2b(p);
}

extern "C" void kernel_launch(void* const* d_in, const int* in_sizes, int n_in,
                              void* d_out, int out_size, void* d_ws, size_t ws_size,
                              hipStream_t stream) {
    const void* x  = d_in[0];
    const int* edge_index = (const int*)d_in[1];
    const void* W1 = d_in[2];
    const void* b1 = d_in[3];
    const void* W2 = d_in[4];
    const void* b2 = d_in[5];

    const int N = in_sizes[0] / D_IN;   // 50000
    const int E = in_sizes[1] / 2;      // 800000
    const int* dst = edge_index + E;

    char* ws = (char*)d_ws;
    size_t off = 0;
    auto alloc = [&](size_t bytes) {
        char* p = ws + off;
        off = (off + bytes + 255) & ~(size_t)255;
        return p;
    };
    int* flag     = (int*)alloc(256);
    float* dinv   = (float*)alloc((size_t)N * 4);
    int* counts   = (int*)alloc((size_t)N * 4);
    int* indptr   = (int*)alloc((size_t)(N + 1) * 4);
    int* cursor   = (int*)alloc((size_t)N * 4);
    int* partial  = (int*)alloc(64 * 4);
    int* csr_src  = (int*)alloc((size_t)E * 4);
    int* csr_dst  = (int*)alloc((size_t)E * 4);
    int* pos_of   = (int*)alloc((size_t)E * 4);
    float* ptmp   = (float*)alloc((size_t)E * 4);
    unsigned short* Wp1 = (unsigned short*)alloc((size_t)D_IN * 256 * 2);
    unsigned short* Wp2 = (unsigned short*)alloc((size_t)D_HID * 256 * 2);
    unsigned short* hA  = (unsigned short*)alloc((size_t)N * 256 * 2);    // 25.6 MB
    unsigned short* hB  = (unsigned short*)alloc((size_t)N * 256 * 2);    // 25.6 MB

    const int nb = (N + 1023) / 1024;   // 49 <= 64
    const int sblocks = (E + 255) / 256;            // 3125
    const int fblocks = (N + 255) / 256;            // 196
    const int wp1Blocks = (D_IN * 32) / 256;        // 64
    const int wp2Blocks = (D_HID * 32) / 256;       // 32
    const int ggrid = (N + 63) / 64;                // 782

    hipMemsetAsync(flag, 0, 4, stream);
    hipMemsetAsync(counts, 0, (size_t)N * 4, stream);
    detect_dtype_kernel<<<64, 256, 0, stream>>>((const ushort4*)x, 16384, flag);
    pre_fused_kernel<<<sblocks + wp1Blocks + wp2Blocks, 256, 0, stream>>>(
        dst, counts, E, W1, Wp1, W2, Wp2, flag, sblocks, wp1Blocks);
    partial_sum_kernel<<<nb, 256, 0, stream>>>(counts, partial, N);
    scan_partials_kernel<<<1, 64, 0, stream>>>(partial, nb, indptr, N);
    scan_chunk_kernel<<<nb, 1024, 0, stream>>>(counts, partial, indptr, cursor, dinv, N);

    // gemm1 (blocks first) + CSR scatter + csr_dst run-fill, one launch
    gemm_bf16<D_IN, true, true><<<ggrid + sblocks + fblocks, 256, 0, stream>>>(
        x, Wp1, hA, N, flag, edge_index, cursor, csr_src, csr_dst, pos_of, indptr, E, sblocks);
    // fused aggregate(+b1, relu) @ W2: hA gathers -> hB = h1@W2 (h1 never materialized)
    agg_gemm_kernel<<<ggrid, 256, 0, stream>>>(hA, indptr, csr_src, dinv, b1, Wp2, hB, N, flag);
    // layer-2 aggregation: hB gathers -> hA = h2
    aggregate_kernel<<<(N + 3) / 4, 256, 0, stream>>>(hB, indptr, csr_src, dinv, b2, hA, N, 0, flag);
    edge_score_mfma<<<(E + 63) / 64, 256, 0, stream>>>(hA, csr_src, csr_dst, ptmp, E);
    permute_out_kernel<<<(E + 255) / 256, 256, 0, stream>>>(ptmp, pos_of, d_out, E, flag);
}

// Round 10
// 461.909 us; speedup vs baseline: 1.1650x; 1.1650x over previous
//
#include <hip/hip_runtime.h>
#include <stdint.h>

#define D_IN 512
#define D_HID 256

typedef __attribute__((ext_vector_type(8))) short bf16x8;
typedef __attribute__((ext_vector_type(8))) unsigned short u16x8;
typedef __attribute__((ext_vector_type(4))) float f32x4;

__device__ __forceinline__ float b2f(unsigned short u) {
    union { float f; uint32_t i; } x; x.i = ((uint32_t)u) << 16; return x.f;
}
__device__ __forceinline__ unsigned short f2b(float f) {
    union { float f; uint32_t i; } x; x.f = f;
    uint32_t i = x.i;
    uint32_t r = (i + 0x7FFFu + ((i >> 16) & 1u)) >> 16;
    return (unsigned short)r;
}

// async global->LDS 16B copy; dest is wave-uniform base + lane*16 (HW rule)
__device__ __forceinline__ void async_copy16(const unsigned short* g, unsigned short* lds) {
    __builtin_amdgcn_global_load_lds((const __attribute__((address_space(1))) unsigned int*)g,
                                     (__attribute__((address_space(3))) unsigned int*)lds,
                                     16, 0, 0);
}

// ---------- dtype detector (parallel): flag|=1 if raw bits are float32 ----------
__global__ __launch_bounds__(256) void detect_dtype_kernel(const ushort4* __restrict__ raw,
                                                           int n4, int* __restrict__ flag) {
    int i = blockIdx.x * blockDim.x + threadIdx.x;
    int hit = 0;
    if (i < n4) {
        ushort4 u = raw[i];
        hit = ((((u.x >> 7) & 0xFF) == 0xFF) || (((u.y >> 7) & 0xFF) == 0xFF) ||
               (((u.z >> 7) & 0xFF) == 0xFF) || (((u.w >> 7) & 0xFF) == 0xFF)) ? 1 : 0;
    }
    unsigned long long b = __ballot(hit);
    if ((threadIdx.x & 63) == 0 && b != 0ULL) atomicOr(flag, 1);
}

// ---------- W pack body: fragment order ----------
//   Wp[(((kk*2 + h)*16 + c)*64 + lane)*8 + j] = W[kk*64 + h*32 + (lane>>4)*8 + j][c*16 + (lane&15)]
// One wave B-fragment load = 1 KB contiguous (validated r6).
__device__ __forceinline__ void wpack_body(const void* __restrict__ W,
        unsigned short* __restrict__ Wp, int K, bool f32, int t) {
    int total = (K >> 6) * 2 * 16 * 64;
    if (t >= total) return;
    int lane = t & 63;
    int c = (t >> 6) & 15;
    int h = (t >> 10) & 1;
    int kk = t >> 11;
    int n = c * 16 + (lane & 15);
    int k0 = kk * 64 + h * 32 + (lane >> 4) * 8;
    u16x8 o;
#pragma unroll
    for (int j = 0; j < 8; ++j) {
        float v = f32 ? ((const float*)W)[(size_t)(k0 + j) * 256 + n]
                      : b2f(((const unsigned short*)W)[(size_t)(k0 + j) * 256 + n]);
        o[j] = f2b(v);
    }
    *(u16x8*)(Wp + (size_t)t * 8) = o;
}

// ---------- fused independent pre-work: hist (long pole) + wpack1 + wpack2 ----------
__global__ __launch_bounds__(256) void pre_fused_kernel(const int* __restrict__ dst,
        int* __restrict__ counts, int E,
        const void* __restrict__ W1, unsigned short* __restrict__ Wp1,
        const void* __restrict__ W2, unsigned short* __restrict__ Wp2,
        const int* __restrict__ flag, int histBlocks, int wp1Blocks) {
    int b = blockIdx.x;
    if (b < histBlocks) {
        int e = b * 256 + threadIdx.x;
        if (e < E) atomicAdd(&counts[dst[e]], 1);
        return;
    }
    b -= histBlocks;
    bool f32 = (*flag != 0);
    if (b < wp1Blocks) {
        wpack_body(W1, Wp1, D_IN, f32, b * 256 + threadIdx.x);
    } else {
        wpack_body(W2, Wp2, D_HID, f32, (b - wp1Blocks) * 256 + threadIdx.x);
    }
}

// ---------- parallel scan P1/P2/P3 ----------
__global__ __launch_bounds__(256) void partial_sum_kernel(const int* __restrict__ counts,
        int* __restrict__ partial, int n) {
    __shared__ int sh[4];
    int b = blockIdx.x;
    int lane = threadIdx.x & 63, wv = threadIdx.x >> 6;
    int s = 0;
    for (int j = threadIdx.x; j < 1024; j += 256) {
        int i = b * 1024 + j;
        s += (i < n) ? counts[i] : 0;
    }
#pragma unroll
    for (int off = 32; off > 0; off >>= 1) s += __shfl_down(s, off, 64);
    if (lane == 0) sh[wv] = s;
    __syncthreads();
    if (threadIdx.x == 0) partial[b] = sh[0] + sh[1] + sh[2] + sh[3];
}

__global__ void scan_partials_kernel(int* __restrict__ partial, int nb,
                                     int* __restrict__ indptr, int N) {
    int lane = threadIdx.x & 63;
    int orig = (lane < nb) ? partial[lane] : 0;
    int v = orig;
#pragma unroll
    for (int off = 1; off < 64; off <<= 1) {
        int u = __shfl(v, lane - off, 64);
        if (lane >= off) v += u;
    }
    int tot = __shfl(v, nb - 1, 64);
    if (lane < nb) partial[lane] = v - orig;
    if (lane == 0) indptr[N] = tot;
}

__global__ __launch_bounds__(1024) void scan_chunk_kernel(const int* __restrict__ counts,
        const int* __restrict__ partial, int* __restrict__ indptr, int* __restrict__ cursor,
        float* __restrict__ dinv, int n) {
    __shared__ int sh[1024];
    int b = blockIdx.x;
    int i = b * 1024 + threadIdx.x;
    int v = (i < n) ? counts[i] : 0;
    sh[threadIdx.x] = v;
    __syncthreads();
    for (int off = 1; off < 1024; off <<= 1) {
        int t = (threadIdx.x >= off) ? sh[threadIdx.x - off] : 0;
        __syncthreads();
        sh[threadIdx.x] += t;
        __syncthreads();
    }
    if (i < n) {
        int e = partial[b] + sh[threadIdx.x] - v;
        indptr[i] = e;
        cursor[i] = e;
        dinv[i] = rsqrtf((float)(v + 1));
    }
}

// ---------- MFMA GEMM: C[M,256] = A[M,K] @ W[K,256], fused (FUSE) with:
//   tail range 1: CSR scatter (atomic; csr_src scattered + pos_of coalesced only --
//                 csr_dst scattered stream removed: 8x cross-XCD write amplification)
//   tail range 2: csr_dst run-fill from indptr (coalesced)
// gemm blocks FIRST so BW-bound work starts immediately.
// gemm: 256 thr / 4 waves; tile 64 rows x 256 cols; BK=64, double-buffered A via
// async_copy16 (bf16) or reg-staged f32->bf16 (MF32 && *flag). B from fragment-
// packed Wp (8 x 1KB coalesced/step). LDS: 128B rows, seg rotation (seg+row)&7.
template<int K, bool MF32, bool FUSE>
__global__ __launch_bounds__(256) void gemm_bf16(const void* __restrict__ Ain,
        const unsigned short* __restrict__ Wp, unsigned short* __restrict__ C, int M,
        const int* __restrict__ flag,
        const int* __restrict__ eidx, int* __restrict__ cursor, int* __restrict__ csr_src,
        int* __restrict__ csr_dst, int* __restrict__ pos_of,
        const int* __restrict__ indptr, int E, int sblocks) {
    __shared__ unsigned short As[2][64 * 64];    // 2 x 8 KB
    constexpr int NK = K / 64;
    int bid = blockIdx.x;
    int gblocks = (M + 63) >> 6;
    if (FUSE) {
        if (bid >= gblocks) {
            int tb = bid - gblocks;
            if (tb < sblocks) {
                int e = tb * 256 + (int)threadIdx.x;
                if (e < E) {
                    int d = eidx[(size_t)E + e];
                    int pos = atomicAdd(&cursor[d], 1);
                    csr_src[pos] = eidx[e];
                    pos_of[e] = pos;
                }
            } else {
                int v = (tb - sblocks) * 256 + (int)threadIdx.x;
                if (v < M) {
                    int b0 = indptr[v], e0 = indptr[v + 1];
                    for (int p = b0; p < e0; ++p) csr_dst[p] = v;
                }
            }
            return;
        }
    }
    int t = threadIdx.x;
    int lane = t & 63, wv = t >> 6;
    int n0 = lane & 15, grp = lane >> 4;
    int row0 = bid * 64;

    int srow = wv * 16 + (lane >> 3);         // + j*8 added per issue
    int segp = lane & 7;

    f32x4 acc[4][4];
#pragma unroll
    for (int rt = 0; rt < 4; ++rt)
#pragma unroll
        for (int ct = 0; ct < 4; ++ct) acc[rt][ct] = (f32x4){0.f, 0.f, 0.f, 0.f};

    auto compute_tile = [&](int kk, const unsigned short* Abuf) {
        bf16x8 bw[4][2];
#pragma unroll
        for (int ct = 0; ct < 4; ++ct)
#pragma unroll
            for (int h = 0; h < 2; ++h)
                bw[ct][h] = *(const bf16x8*)(Wp +
                    ((size_t)(((kk * 2 + h) * 16) + (wv * 4 + ct)) * 64 + lane) * 8);
#pragma unroll
        for (int rt = 0; rt < 4; ++rt) {
            int r = rt * 16 + n0;
#pragma unroll
            for (int h = 0; h < 2; ++h) {
                int sp = (h * 4 + grp + r) & 7;
                bf16x8 a = *(const bf16x8*)(Abuf + r * 64 + sp * 8);
#pragma unroll
                for (int ct = 0; ct < 4; ++ct)
                    acc[rt][ct] = __builtin_amdgcn_mfma_f32_16x16x32_bf16(a, bw[ct][h],
                                                                          acc[rt][ct], 0, 0, 0);
            }
        }
    };

    bool f32src = MF32 && (*flag != 0);
    if (f32src) {
        const float* A = (const float*)Ain;
        auto stage_f32 = [&](int buf, const float4* pr) {
#pragma unroll
            for (int j = 0; j < 2; ++j) {
                u16x8 o;
#pragma unroll
                for (int q = 0; q < 4; ++q) {
                    o[q]     = f2b(pr[j * 2 + 0][q]);
                    o[q + 4] = f2b(pr[j * 2 + 1][q]);
                }
                *(u16x8*)(&As[buf][0] + wv * 1024 + j * 512 + lane * 8) = o;
            }
        };
        auto load_f32 = [&](int kof, float4* pr) {
#pragma unroll
            for (int j = 0; j < 2; ++j) {
                int row = srow + j * 8;
                int s = (segp - row) & 7;
                const float* g = A + (size_t)min(row0 + row, M - 1) * K + kof + s * 8;
                pr[j * 2 + 0] = *(const float4*)(g);
                pr[j * 2 + 1] = *(const float4*)(g + 4);
            }
        };
        float4 pr[4];
        load_f32(0, pr);
        stage_f32(0, pr);
        for (int kk = 0; kk < NK; ++kk) {
            int cur = kk & 1;
            if (kk + 1 < NK) load_f32((kk + 1) * 64, pr);   // in flight across compute
            asm volatile("s_waitcnt lgkmcnt(0)" ::: "memory");  // my ds_writes done
            __builtin_amdgcn_s_barrier();                       // buf[cur] visible to all
            compute_tile(kk, &As[cur][0]);
            if (kk + 1 < NK) stage_f32(cur ^ 1, pr);
        }
    } else {
        const unsigned short* A = (const unsigned short*)Ain;
#pragma unroll
        for (int j = 0; j < 2; ++j) {
            int row = srow + j * 8;
            int s = (segp - row) & 7;
            const unsigned short* g = A + (size_t)min(row0 + row, M - 1) * K + s * 8;
            async_copy16(g, &As[0][0] + wv * 1024 + j * 512);
        }
        asm volatile("s_waitcnt vmcnt(0)" ::: "memory");
        __builtin_amdgcn_s_barrier();
        for (int kk = 0; kk < NK; ++kk) {
            int cur = kk & 1;
            if (kk + 1 < NK) {
                int kof = (kk + 1) * 64;
#pragma unroll
                for (int j = 0; j < 2; ++j) {
                    int row = srow + j * 8;
                    int s = (segp - row) & 7;
                    const unsigned short* g = A + (size_t)min(row0 + row, M - 1) * K + kof + s * 8;
                    async_copy16(g, &As[cur ^ 1][0] + wv * 1024 + j * 512);
                }
            }
            compute_tile(kk, &As[cur][0]);
            asm volatile("s_waitcnt vmcnt(0)" ::: "memory");
            __builtin_amdgcn_s_barrier();
        }
    }
#pragma unroll
    for (int rt = 0; rt < 4; ++rt) {
#pragma unroll
        for (int ct = 0; ct < 4; ++ct) {
#pragma unroll
            for (int reg = 0; reg < 4; ++reg) {
                int row = row0 + rt * 16 + grp * 4 + reg;
                if (row < M)
                    C[(size_t)row * 256 + (wv * 4 + ct) * 16 + n0] = f2b(acc[rt][ct][reg]);
            }
        }
    }
}

// ---------- GCN aggregation (bf16 h in, bf16 out, f32 accum) ----------
// Two 32-lane halves x mov-free 3-stage rotation; 6 row-loads (3 KB) in flight/wave.
// At the gather request-rate ceiling (~410 MB requested / ~64 us = 6.3 TB/s).
// r9 lesson: do NOT fuse this with LDS-heavy GEMM -- gather throughput scales with
// occupancy (68% here vs 18% fused = 159 us regression).
__global__ __launch_bounds__(256) void aggregate_kernel(const unsigned short* __restrict__ h,
        const int* __restrict__ indptr, const int* __restrict__ csr_src,
        const float* __restrict__ dinv, const void* __restrict__ bias,
        unsigned short* __restrict__ out, int n, int do_relu, const int* __restrict__ flag) {
    int wave = threadIdx.x >> 6;
    int lane = threadIdx.x & 63;
    int half = lane >> 5;
    int hl = lane & 31;
    int v = blockIdx.x * 4 + wave;
    if (v >= n) return;
    int beg = indptr[v];
    int end = indptr[v + 1];
    float dv = dinv[v];

    float acc[8];
    if (half == 0) {
        u16x8 hv = *(const u16x8*)(h + (size_t)v * 256 + hl * 8);
#pragma unroll
        for (int i = 0; i < 8; ++i) acc[i] = dv * b2f(hv[i]);
    } else {
#pragma unroll
        for (int i = 0; i < 8; ++i) acc[i] = 0.f;
    }

    float wA = 0.f, wB = 0.f, wC = 0.f;
    u16x8 rA = (u16x8)0, rB = (u16x8)0, rC = (u16x8)0;
    auto ld = [&](int idx, float& w, u16x8& r) {
        if (idx < end) {
            int s = csr_src[idx];
            w = dinv[s];
            r = *(const u16x8*)(h + (size_t)s * 256 + hl * 8);
        } else {
            w = 0.f;
        }
    };
    int e = beg + half;
    ld(e, wA, rA);
    ld(e + 2, wB, rB);
    ld(e + 4, wC, rC);
    while (e + 4 < end) {
#pragma unroll
        for (int i = 0; i < 8; ++i) acc[i] += wA * b2f(rA[i]);
        ld(e + 6, wA, rA);
#pragma unroll
        for (int i = 0; i < 8; ++i) acc[i] += wB * b2f(rB[i]);
        ld(e + 8, wB, rB);
#pragma unroll
        for (int i = 0; i < 8; ++i) acc[i] += wC * b2f(rC[i]);
        ld(e + 10, wC, rC);
        e += 6;
    }
#pragma unroll
    for (int i = 0; i < 8; ++i)
        acc[i] += wA * b2f(rA[i]) + wB * b2f(rB[i]) + wC * b2f(rC[i]);

#pragma unroll
    for (int i = 0; i < 8; ++i) acc[i] += __shfl_xor(acc[i], 32, 64);

    if (half == 0) {
        float bb[8];
        if (*flag != 0) {
            const float* bp = (const float*)bias + hl * 8;
#pragma unroll
            for (int i = 0; i < 8; ++i) bb[i] = bp[i];
        } else {
            const unsigned short* bp = (const unsigned short*)bias + hl * 8;
#pragma unroll
            for (int i = 0; i < 8; ++i) bb[i] = b2f(bp[i]);
        }
        u16x8 ov;
#pragma unroll
        for (int i = 0; i < 8; ++i) {
            float o = dv * acc[i] + bb[i];
            if (do_relu) o = fmaxf(o, 0.f);
            ov[i] = f2b(o);
        }
        *(u16x8*)(out + (size_t)v * 256 + hl * 8) = ov;
    }
}

// ---------- edge scoring via MFMA: 16 CSR-ordered edges per wave ----------
// CSR order keeps h[dst] cache-resident; h[src] is the irreducible random gather.
// Output to CSR-ordered f32 tmp (coalesced); permute pass restores edge order.
__global__ __launch_bounds__(256) void edge_score_mfma(const unsigned short* __restrict__ h,
        const int* __restrict__ csr_src, const int* __restrict__ csr_dst,
        float* __restrict__ tmp, int E) {
    int lane = threadIdx.x & 63;
    int wv = threadIdx.x >> 6;
    int base = (blockIdx.x * 4 + wv) * 16;
    if (base >= E) return;
    int m = lane & 15, grp = lane >> 4;
    int e = base + m;
    int ec = min(e, E - 1);
    int s = csr_src[ec], d = csr_dst[ec];
    const unsigned short* hs = h + (size_t)s * 256 + grp * 8;
    const unsigned short* hd = h + (size_t)d * 256 + grp * 8;
    f32x4 acc = {0.f, 0.f, 0.f, 0.f};
#pragma unroll
    for (int kk = 0; kk < 8; ++kk) {
        bf16x8 a = *(const bf16x8*)(hs + kk * 32);
        bf16x8 b = *(const bf16x8*)(hd + kk * 32);
        acc = __builtin_amdgcn_mfma_f32_16x16x32_bf16(a, b, acc, 0, 0, 0);
    }
    int reg = m - grp * 4;
    if (reg >= 0 && reg < 4 && e < E) {
        float p = (reg == 0) ? acc[0] : (reg == 1) ? acc[1] : (reg == 2) ? acc[2] : acc[3];
        tmp[e] = 1.f / (1.f + __expf(-p));   // CSR-slot order: coalesced
    }
}

// out[e] = tmp[pos_of[e]] -- L2/L3-resident gather + sequential write.
__global__ __launch_bounds__(256) void permute_out_kernel(const float* __restrict__ tmp,
        const int* __restrict__ pos_of, void* __restrict__ out, int E,
        const int* __restrict__ flag) {
    int e = blockIdx.x * blockDim.x + threadIdx.x;
    if (e >= E) return;
    float p = tmp[pos_of[e]];
    if (*flag != 0)
        ((float*)out)[e] = p;
    else
        ((unsigned short*)out)[e] = f2b(p);
}

extern "C" void kernel_launch(void* const* d_in, const int* in_sizes, int n_in,
                              void* d_out, int out_size, void* d_ws, size_t ws_size,
                              hipStream_t stream) {
    const void* x  = d_in[0];
    const int* edge_index = (const int*)d_in[1];
    const void* W1 = d_in[2];
    const void* b1 = d_in[3];
    const void* W2 = d_in[4];
    const void* b2 = d_in[5];

    const int N = in_sizes[0] / D_IN;   // 50000
    const int E = in_sizes[1] / 2;      // 800000
    const int* dst = edge_index + E;

    char* ws = (char*)d_ws;
    size_t off = 0;
    auto alloc = [&](size_t bytes) {
        char* p = ws + off;
        off = (off + bytes + 255) & ~(size_t)255;
        return p;
    };
    int* flag     = (int*)alloc(256);
    float* dinv   = (float*)alloc((size_t)N * 4);
    int* counts   = (int*)alloc((size_t)N * 4);
    int* indptr   = (int*)alloc((size_t)(N + 1) * 4);
    int* cursor   = (int*)alloc((size_t)N * 4);
    int* partial  = (int*)alloc(64 * 4);
    int* csr_src  = (int*)alloc((size_t)E * 4);
    int* csr_dst  = (int*)alloc((size_t)E * 4);
    int* pos_of   = (int*)alloc((size_t)E * 4);
    float* ptmp   = (float*)alloc((size_t)E * 4);
    unsigned short* Wp1 = (unsigned short*)alloc((size_t)D_IN * 256 * 2);
    unsigned short* Wp2 = (unsigned short*)alloc((size_t)D_HID * 256 * 2);
    unsigned short* hA  = (unsigned short*)alloc((size_t)N * 256 * 2);    // 25.6 MB
    unsigned short* hB  = (unsigned short*)alloc((size_t)N * 256 * 2);    // 25.6 MB

    const int nb = (N + 1023) / 1024;   // 49 <= 64
    const int sblocks = (E + 255) / 256;            // 3125
    const int fblocks = (N + 255) / 256;            // 196
    const int wp1Blocks = (D_IN * 32) / 256;        // 64
    const int wp2Blocks = (D_HID * 32) / 256;       // 32
    const int ggrid = (N + 63) / 64;                // 782

    hipMemsetAsync(flag, 0, 4, stream);
    hipMemsetAsync(counts, 0, (size_t)N * 4, stream);
    detect_dtype_kernel<<<64, 256, 0, stream>>>((const ushort4*)x, 16384, flag);
    pre_fused_kernel<<<sblocks + wp1Blocks + wp2Blocks, 256, 0, stream>>>(
        dst, counts, E, W1, Wp1, W2, Wp2, flag, sblocks, wp1Blocks);
    partial_sum_kernel<<<nb, 256, 0, stream>>>(counts, partial, N);
    scan_partials_kernel<<<1, 64, 0, stream>>>(partial, nb, indptr, N);
    scan_chunk_kernel<<<nb, 1024, 0, stream>>>(counts, partial, indptr, cursor, dinv, N);

    // gemm1 (blocks first) + CSR scatter (csr_src+pos_of only) + csr_dst run-fill
    gemm_bf16<D_IN, true, true><<<ggrid + sblocks + fblocks, 256, 0, stream>>>(
        x, Wp1, hA, N, flag, edge_index, cursor, csr_src, csr_dst, pos_of, indptr, E, sblocks);
    aggregate_kernel<<<(N + 3) / 4, 256, 0, stream>>>(hA, indptr, csr_src, dinv, b1, hB, N, 1, flag);
    gemm_bf16<D_HID, false, false><<<ggrid, 256, 0, stream>>>(
        hB, Wp2, hA, N, flag, nullptr, nullptr, nullptr, nullptr, nullptr, nullptr, 0, 0);
    aggregate_kernel<<<(N + 3) / 4, 256, 0, stream>>>(hA, indptr, csr_src, dinv, b2, hB, N, 0, flag);
    edge_score_mfma<<<(E + 63) / 64, 256, 0, stream>>>(hB, csr_src, csr_dst, ptmp, E);
    permute_out_kernel<<<(E + 255) / 256, 256, 0, stream>>>(ptmp, pos_of, d_out, E, flag);
}

// Round 12
// 444.256 us; speedup vs baseline: 1.2113x; 1.0397x over previous
//
#include <hip/hip_runtime.h>
#include <stdint.h>

#define D_IN 512
#define D_HID 256

typedef __attribute__((ext_vector_type(8))) short bf16x8;
typedef __attribute__((ext_vector_type(8))) unsigned short u16x8;
typedef __attribute__((ext_vector_type(4))) float f32x4;

__device__ __forceinline__ float b2f(unsigned short u) {
    union { float f; uint32_t i; } x; x.i = ((uint32_t)u) << 16; return x.f;
}
__device__ __forceinline__ unsigned short f2b(float f) {
    union { float f; uint32_t i; } x; x.f = f;
    uint32_t i = x.i;
    uint32_t r = (i + 0x7FFFu + ((i >> 16) & 1u)) >> 16;
    return (unsigned short)r;
}

// async global->LDS 16B copy; dest is wave-uniform base + lane*16 (HW rule)
__device__ __forceinline__ void async_copy16(const unsigned short* g, unsigned short* lds) {
    __builtin_amdgcn_global_load_lds((const __attribute__((address_space(1))) unsigned int*)g,
                                     (__attribute__((address_space(3))) unsigned int*)lds,
                                     16, 0, 0);
}

// ---------- dtype detector (parallel): flag|=1 if raw bits are float32 ----------
__global__ __launch_bounds__(256) void detect_dtype_kernel(const ushort4* __restrict__ raw,
                                                           int n4, int* __restrict__ flag) {
    int i = blockIdx.x * blockDim.x + threadIdx.x;
    int hit = 0;
    if (i < n4) {
        ushort4 u = raw[i];
        hit = ((((u.x >> 7) & 0xFF) == 0xFF) || (((u.y >> 7) & 0xFF) == 0xFF) ||
               (((u.z >> 7) & 0xFF) == 0xFF) || (((u.w >> 7) & 0xFF) == 0xFF)) ? 1 : 0;
    }
    unsigned long long b = __ballot(hit);
    if ((threadIdx.x & 63) == 0 && b != 0ULL) atomicOr(flag, 1);
}

// ---------- W pack body: fragment order ----------
//   Wp[(((kk*2 + h)*16 + c)*64 + lane)*8 + j] = W[kk*64 + h*32 + (lane>>4)*8 + j][c*16 + (lane&15)]
// One wave B-fragment load = 1 KB contiguous (validated r6).
__device__ __forceinline__ void wpack_body(const void* __restrict__ W,
        unsigned short* __restrict__ Wp, int K, bool f32, int t) {
    int total = (K >> 6) * 2 * 16 * 64;
    if (t >= total) return;
    int lane = t & 63;
    int c = (t >> 6) & 15;
    int h = (t >> 10) & 1;
    int kk = t >> 11;
    int n = c * 16 + (lane & 15);
    int k0 = kk * 64 + h * 32 + (lane >> 4) * 8;
    u16x8 o;
#pragma unroll
    for (int j = 0; j < 8; ++j) {
        float v = f32 ? ((const float*)W)[(size_t)(k0 + j) * 256 + n]
                      : b2f(((const unsigned short*)W)[(size_t)(k0 + j) * 256 + n]);
        o[j] = f2b(v);
    }
    *(u16x8*)(Wp + (size_t)t * 8) = o;
}

// ---------- fused independent pre-work: hist (long pole) + wpack1 + wpack2 ----------
// Hist captures the atomicAdd RETURN VALUE as within[e] (within-node rank):
// the CSR slot later becomes indptr[d] + within[e] with NO second atomic pass.
__global__ __launch_bounds__(256) void pre_fused_kernel(const int* __restrict__ dst,
        int* __restrict__ counts, int* __restrict__ within, int E,
        const void* __restrict__ W1, unsigned short* __restrict__ Wp1,
        const void* __restrict__ W2, unsigned short* __restrict__ Wp2,
        const int* __restrict__ flag, int histBlocks, int wp1Blocks) {
    int b = blockIdx.x;
    if (b < histBlocks) {
        int e = b * 256 + threadIdx.x;
        if (e < E) within[e] = atomicAdd(&counts[dst[e]], 1);
        return;
    }
    b -= histBlocks;
    bool f32 = (*flag != 0);
    if (b < wp1Blocks) {
        wpack_body(W1, Wp1, D_IN, f32, b * 256 + threadIdx.x);
    } else {
        wpack_body(W2, Wp2, D_HID, f32, (b - wp1Blocks) * 256 + threadIdx.x);
    }
}

// ---------- parallel scan P1/P2/P3 ----------
__global__ __launch_bounds__(256) void partial_sum_kernel(const int* __restrict__ counts,
        int* __restrict__ partial, int n) {
    __shared__ int sh[4];
    int b = blockIdx.x;
    int lane = threadIdx.x & 63, wv = threadIdx.x >> 6;
    int s = 0;
    for (int j = threadIdx.x; j < 1024; j += 256) {
        int i = b * 1024 + j;
        s += (i < n) ? counts[i] : 0;
    }
#pragma unroll
    for (int off = 32; off > 0; off >>= 1) s += __shfl_down(s, off, 64);
    if (lane == 0) sh[wv] = s;
    __syncthreads();
    if (threadIdx.x == 0) partial[b] = sh[0] + sh[1] + sh[2] + sh[3];
}

__global__ void scan_partials_kernel(int* __restrict__ partial, int nb,
                                     int* __restrict__ indptr, int N) {
    int lane = threadIdx.x & 63;
    int orig = (lane < nb) ? partial[lane] : 0;
    int v = orig;
#pragma unroll
    for (int off = 1; off < 64; off <<= 1) {
        int u = __shfl(v, lane - off, 64);
        if (lane >= off) v += u;
    }
    int tot = __shfl(v, nb - 1, 64);
    if (lane < nb) partial[lane] = v - orig;
    if (lane == 0) indptr[N] = tot;
}

__global__ __launch_bounds__(1024) void scan_chunk_kernel(const int* __restrict__ counts,
        const int* __restrict__ partial, int* __restrict__ indptr,
        float* __restrict__ dinv, int n) {
    __shared__ int sh[1024];
    int b = blockIdx.x;
    int i = b * 1024 + threadIdx.x;
    int v = (i < n) ? counts[i] : 0;
    sh[threadIdx.x] = v;
    __syncthreads();
    for (int off = 1; off < 1024; off <<= 1) {
        int t = (threadIdx.x >= off) ? sh[threadIdx.x - off] : 0;
        __syncthreads();
        sh[threadIdx.x] += t;
        __syncthreads();
    }
    if (i < n) {
        int e = partial[b] + sh[threadIdx.x] - v;
        indptr[i] = e;
        dinv[i] = rsqrtf((float)(v + 1));
    }
}

// ---------- MFMA GEMM: C[M,256] = A[M,K] @ W[K,256], fused (FUSE) with:
//   tail range 1: ATOMIC-FREE CSR fill: pos = indptr[d] + within[e] (rank captured
//                 in hist). Coalesced reads + one fire-and-forget scattered 4B store
//                 -- nothing blocks, so inheriting the gemm's low occupancy is fine.
//   tail range 2: csr_dst run-fill from indptr (coalesced)
// gemm blocks FIRST so BW-bound work starts immediately.
// gemm: 256 thr / 4 waves; tile 64 rows x 256 cols; BK=64, double-buffered A via
// async_copy16 (bf16) or reg-staged f32->bf16 (MF32 && *flag). B from fragment-
// packed Wp (8 x 1KB coalesced/step). LDS: 128B rows, seg rotation (seg+row)&7.
template<int K, bool MF32, bool FUSE>
__global__ __launch_bounds__(256) void gemm_bf16(const void* __restrict__ Ain,
        const unsigned short* __restrict__ Wp, unsigned short* __restrict__ C, int M,
        const int* __restrict__ flag,
        const int* __restrict__ eidx, const int* __restrict__ within,
        int* __restrict__ csr_src, int* __restrict__ csr_dst, int* __restrict__ pos_of,
        const int* __restrict__ indptr, int E, int sblocks) {
    __shared__ unsigned short As[2][64 * 64];    // 2 x 8 KB
    constexpr int NK = K / 64;
    int bid = blockIdx.x;
    int gblocks = (M + 63) >> 6;
    if (FUSE) {
        if (bid >= gblocks) {
            int tb = bid - gblocks;
            if (tb < sblocks) {
                int e = tb * 256 + (int)threadIdx.x;
                if (e < E) {
                    int d = eidx[(size_t)E + e];
                    int pos = indptr[d] + within[e];     // no atomic
                    csr_src[pos] = eidx[e];              // scattered store (non-blocking)
                    pos_of[e] = pos;                     // coalesced
                }
            } else {
                int v = (tb - sblocks) * 256 + (int)threadIdx.x;
                if (v < M) {
                    int b0 = indptr[v], e0 = indptr[v + 1];
                    for (int p = b0; p < e0; ++p) csr_dst[p] = v;
                }
            }
            return;
        }
    }
    int t = threadIdx.x;
    int lane = t & 63, wv = t >> 6;
    int n0 = lane & 15, grp = lane >> 4;
    int row0 = bid * 64;

    int srow = wv * 16 + (lane >> 3);         // + j*8 added per issue
    int segp = lane & 7;

    f32x4 acc[4][4];
#pragma unroll
    for (int rt = 0; rt < 4; ++rt)
#pragma unroll
        for (int ct = 0; ct < 4; ++ct) acc[rt][ct] = (f32x4){0.f, 0.f, 0.f, 0.f};

    auto compute_tile = [&](int kk, const unsigned short* Abuf) {
        bf16x8 bw[4][2];
#pragma unroll
        for (int ct = 0; ct < 4; ++ct)
#pragma unroll
            for (int h = 0; h < 2; ++h)
                bw[ct][h] = *(const bf16x8*)(Wp +
                    ((size_t)(((kk * 2 + h) * 16) + (wv * 4 + ct)) * 64 + lane) * 8);
#pragma unroll
        for (int rt = 0; rt < 4; ++rt) {
            int r = rt * 16 + n0;
#pragma unroll
            for (int h = 0; h < 2; ++h) {
                int sp = (h * 4 + grp + r) & 7;
                bf16x8 a = *(const bf16x8*)(Abuf + r * 64 + sp * 8);
#pragma unroll
                for (int ct = 0; ct < 4; ++ct)
                    acc[rt][ct] = __builtin_amdgcn_mfma_f32_16x16x32_bf16(a, bw[ct][h],
                                                                          acc[rt][ct], 0, 0, 0);
            }
        }
    };

    bool f32src = MF32 && (*flag != 0);
    if (f32src) {
        const float* A = (const float*)Ain;
        auto stage_f32 = [&](int buf, const float4* pr) {
#pragma unroll
            for (int j = 0; j < 2; ++j) {
                u16x8 o;
#pragma unroll
                for (int q = 0; q < 4; ++q) {
                    o[q]     = f2b(pr[j * 2 + 0][q]);
                    o[q + 4] = f2b(pr[j * 2 + 1][q]);
                }
                *(u16x8*)(&As[buf][0] + wv * 1024 + j * 512 + lane * 8) = o;
            }
        };
        auto load_f32 = [&](int kof, float4* pr) {
#pragma unroll
            for (int j = 0; j < 2; ++j) {
                int row = srow + j * 8;
                int s = (segp - row) & 7;
                const float* g = A + (size_t)min(row0 + row, M - 1) * K + kof + s * 8;
                pr[j * 2 + 0] = *(const float4*)(g);
                pr[j * 2 + 1] = *(const float4*)(g + 4);
            }
        };
        float4 pr[4];
        load_f32(0, pr);
        stage_f32(0, pr);
        for (int kk = 0; kk < NK; ++kk) {
            int cur = kk & 1;
            if (kk + 1 < NK) load_f32((kk + 1) * 64, pr);   // in flight across compute
            asm volatile("s_waitcnt lgkmcnt(0)" ::: "memory");  // my ds_writes done
            __builtin_amdgcn_s_barrier();                       // buf[cur] visible to all
            compute_tile(kk, &As[cur][0]);
            if (kk + 1 < NK) stage_f32(cur ^ 1, pr);
        }
    } else {
        const unsigned short* A = (const unsigned short*)Ain;
#pragma unroll
        for (int j = 0; j < 2; ++j) {
            int row = srow + j * 8;
            int s = (segp - row) & 7;
            const unsigned short* g = A + (size_t)min(row0 + row, M - 1) * K + s * 8;
            async_copy16(g, &As[0][0] + wv * 1024 + j * 512);
        }
        asm volatile("s_waitcnt vmcnt(0)" ::: "memory");
        __builtin_amdgcn_s_barrier();
        for (int kk = 0; kk < NK; ++kk) {
            int cur = kk & 1;
            if (kk + 1 < NK) {
                int kof = (kk + 1) * 64;
#pragma unroll
                for (int j = 0; j < 2; ++j) {
                    int row = srow + j * 8;
                    int s = (segp - row) & 7;
                    const unsigned short* g = A + (size_t)min(row0 + row, M - 1) * K + kof + s * 8;
                    async_copy16(g, &As[cur ^ 1][0] + wv * 1024 + j * 512);
                }
            }
            compute_tile(kk, &As[cur][0]);
            asm volatile("s_waitcnt vmcnt(0)" ::: "memory");
            __builtin_amdgcn_s_barrier();
        }
    }
#pragma unroll
    for (int rt = 0; rt < 4; ++rt) {
#pragma unroll
        for (int ct = 0; ct < 4; ++ct) {
#pragma unroll
            for (int reg = 0; reg < 4; ++reg) {
                int row = row0 + rt * 16 + grp * 4 + reg;
                if (row < M)
                    C[(size_t)row * 256 + (wv * 4 + ct) * 16 + n0] = f2b(acc[rt][ct][reg]);
            }
        }
    }
}

// ---------- GCN aggregation (bf16 h in, bf16 out, f32 accum) ----------
// Two 32-lane halves x mov-free 3-stage rotation; 6 row-loads (3 KB) in flight/wave.
// At the gather request-rate ceiling (~410 MB requested / ~64 us = 6.3 TB/s).
// r9 lesson: do NOT fuse this with LDS-heavy GEMM -- gather throughput scales with
// occupancy (68% here vs 18% fused = 159 us regression).
__global__ __launch_bounds__(256) void aggregate_kernel(const unsigned short* __restrict__ h,
        const int* __restrict__ indptr, const int* __restrict__ csr_src,
        const float* __restrict__ dinv, const void* __restrict__ bias,
        unsigned short* __restrict__ out, int n, int do_relu, const int* __restrict__ flag) {
    int wave = threadIdx.x >> 6;
    int lane = threadIdx.x & 63;
    int half = lane >> 5;
    int hl = lane & 31;
    int v = blockIdx.x * 4 + wave;
    if (v >= n) return;
    int beg = indptr[v];
    int end = indptr[v + 1];
    float dv = dinv[v];

    float acc[8];
    if (half == 0) {
        u16x8 hv = *(const u16x8*)(h + (size_t)v * 256 + hl * 8);
#pragma unroll
        for (int i = 0; i < 8; ++i) acc[i] = dv * b2f(hv[i]);
    } else {
#pragma unroll
        for (int i = 0; i < 8; ++i) acc[i] = 0.f;
    }

    float wA = 0.f, wB = 0.f, wC = 0.f;
    u16x8 rA = (u16x8)0, rB = (u16x8)0, rC = (u16x8)0;
    auto ld = [&](int idx, float& w, u16x8& r) {
        if (idx < end) {
            int s = csr_src[idx];
            w = dinv[s];
            r = *(const u16x8*)(h + (size_t)s * 256 + hl * 8);
        } else {
            w = 0.f;
        }
    };
    int e = beg + half;
    ld(e, wA, rA);
    ld(e + 2, wB, rB);
    ld(e + 4, wC, rC);
    while (e + 4 < end) {
#pragma unroll
        for (int i = 0; i < 8; ++i) acc[i] += wA * b2f(rA[i]);
        ld(e + 6, wA, rA);
#pragma unroll
        for (int i = 0; i < 8; ++i) acc[i] += wB * b2f(rB[i]);
        ld(e + 8, wB, rB);
#pragma unroll
        for (int i = 0; i < 8; ++i) acc[i] += wC * b2f(rC[i]);
        ld(e + 10, wC, rC);
        e += 6;
    }
#pragma unroll
    for (int i = 0; i < 8; ++i)
        acc[i] += wA * b2f(rA[i]) + wB * b2f(rB[i]) + wC * b2f(rC[i]);

#pragma unroll
    for (int i = 0; i < 8; ++i) acc[i] += __shfl_xor(acc[i], 32, 64);

    if (half == 0) {
        float bb[8];
        if (*flag != 0) {
            const float* bp = (const float*)bias + hl * 8;
#pragma unroll
            for (int i = 0; i < 8; ++i) bb[i] = bp[i];
        } else {
            const unsigned short* bp = (const unsigned short*)bias + hl * 8;
#pragma unroll
            for (int i = 0; i < 8; ++i) bb[i] = b2f(bp[i]);
        }
        u16x8 ov;
#pragma unroll
        for (int i = 0; i < 8; ++i) {
            float o = dv * acc[i] + bb[i];
            if (do_relu) o = fmaxf(o, 0.f);
            ov[i] = f2b(o);
        }
        *(u16x8*)(out + (size_t)v * 256 + hl * 8) = ov;
    }
}

// ---------- edge scoring via MFMA: 16 CSR-ordered edges per wave ----------
// CSR order keeps h[dst] cache-resident; h[src] is the irreducible random gather.
// Output to CSR-ordered f32 tmp (coalesced); permute pass restores edge order.
__global__ __launch_bounds__(256) void edge_score_mfma(const unsigned short* __restrict__ h,
        const int* __restrict__ csr_src, const int* __restrict__ csr_dst,
        float* __restrict__ tmp, int E) {
    int lane = threadIdx.x & 63;
    int wv = threadIdx.x >> 6;
    int base = (blockIdx.x * 4 + wv) * 16;
    if (base >= E) return;
    int m = lane & 15, grp = lane >> 4;
    int e = base + m;
    int ec = min(e, E - 1);
    int s = csr_src[ec], d = csr_dst[ec];
    const unsigned short* hs = h + (size_t)s * 256 + grp * 8;
    const unsigned short* hd = h + (size_t)d * 256 + grp * 8;
    f32x4 acc = {0.f, 0.f, 0.f, 0.f};
#pragma unroll
    for (int kk = 0; kk < 8; ++kk) {
        bf16x8 a = *(const bf16x8*)(hs + kk * 32);
        bf16x8 b = *(const bf16x8*)(hd + kk * 32);
        acc = __builtin_amdgcn_mfma_f32_16x16x32_bf16(a, b, acc, 0, 0, 0);
    }
    int reg = m - grp * 4;
    if (reg >= 0 && reg < 4 && e < E) {
        float p = (reg == 0) ? acc[0] : (reg == 1) ? acc[1] : (reg == 2) ? acc[2] : acc[3];
        tmp[e] = 1.f / (1.f + __expf(-p));   // CSR-slot order: coalesced
    }
}

// out[e] = tmp[pos_of[e]] -- L2/L3-resident gather + sequential write.
__global__ __launch_bounds__(256) void permute_out_kernel(const float* __restrict__ tmp,
        const int* __restrict__ pos_of, void* __restrict__ out, int E,
        const int* __restrict__ flag) {
    int e = blockIdx.x * blockDim.x + threadIdx.x;
    if (e >= E) return;
    float p = tmp[pos_of[e]];
    if (*flag != 0)
        ((float*)out)[e] = p;
    else
        ((unsigned short*)out)[e] = f2b(p);
}

extern "C" void kernel_launch(void* const* d_in, const int* in_sizes, int n_in,
                              void* d_out, int out_size, void* d_ws, size_t ws_size,
                              hipStream_t stream) {
    const void* x  = d_in[0];
    const int* edge_index = (const int*)d_in[1];
    const void* W1 = d_in[2];
    const void* b1 = d_in[3];
    const void* W2 = d_in[4];
    const void* b2 = d_in[5];

    const int N = in_sizes[0] / D_IN;   // 50000
    const int E = in_sizes[1] / 2;      // 800000
    const int* dst = edge_index + E;

    char* ws = (char*)d_ws;
    size_t off = 0;
    auto alloc = [&](size_t bytes) {
        char* p = ws + off;
        off = (off + bytes + 255) & ~(size_t)255;
        return p;
    };
    int* flag     = (int*)alloc(256);
    float* dinv   = (float*)alloc((size_t)N * 4);
    int* counts   = (int*)alloc((size_t)N * 4);
    int* indptr   = (int*)alloc((size_t)(N + 1) * 4);
    int* partial  = (int*)alloc(64 * 4);
    int* within   = (int*)alloc((size_t)E * 4);
    int* csr_src  = (int*)alloc((size_t)E * 4);
    int* csr_dst  = (int*)alloc((size_t)E * 4);
    int* pos_of   = (int*)alloc((size_t)E * 4);
    float* ptmp   = (float*)alloc((size_t)E * 4);
    unsigned short* Wp1 = (unsigned short*)alloc((size_t)D_IN * 256 * 2);
    unsigned short* Wp2 = (unsigned short*)alloc((size_t)D_HID * 256 * 2);
    unsigned short* hA  = (unsigned short*)alloc((size_t)N * 256 * 2);    // 25.6 MB
    unsigned short* hB  = (unsigned short*)alloc((size_t)N * 256 * 2);    // 25.6 MB

    const int nb = (N + 1023) / 1024;   // 49 <= 64
    const int sblocks = (E + 255) / 256;            // 3125
    const int fblocks = (N + 255) / 256;            // 196
    const int wp1Blocks = (D_IN * 32) / 256;        // 64
    const int wp2Blocks = (D_HID * 32) / 256;       // 32
    const int ggrid = (N + 63) / 64;                // 782

    hipMemsetAsync(flag, 0, 4, stream);
    hipMemsetAsync(counts, 0, (size_t)N * 4, stream);
    detect_dtype_kernel<<<64, 256, 0, stream>>>((const ushort4*)x, 16384, flag);
    pre_fused_kernel<<<sblocks + wp1Blocks + wp2Blocks, 256, 0, stream>>>(
        dst, counts, within, E, W1, Wp1, W2, Wp2, flag, sblocks, wp1Blocks);
    partial_sum_kernel<<<nb, 256, 0, stream>>>(counts, partial, N);
    scan_partials_kernel<<<1, 64, 0, stream>>>(partial, nb, indptr, N);
    scan_chunk_kernel<<<nb, 1024, 0, stream>>>(counts, partial, indptr, dinv, N);

    // gemm1 (blocks first) + atomic-free CSR fill + csr_dst run-fill, one launch
    gemm_bf16<D_IN, true, true><<<ggrid + sblocks + fblocks, 256, 0, stream>>>(
        x, Wp1, hA, N, flag, edge_index, within, csr_src, csr_dst, pos_of, indptr, E, sblocks);
    aggregate_kernel<<<(N + 3) / 4, 256, 0, stream>>>(hA, indptr, csr_src, dinv, b1, hB, N, 1, flag);
    gemm_bf16<D_HID, false, false><<<ggrid, 256, 0, stream>>>(
        hB, Wp2, hA, N, flag, nullptr, nullptr, nullptr, nullptr, nullptr, nullptr, 0, 0);
    aggregate_kernel<<<(N + 3) / 4, 256, 0, stream>>>(hA, indptr, csr_src, dinv, b2, hB, N, 0, flag);
    edge_score_mfma<<<(E + 63) / 64, 256, 0, stream>>>(hB, csr_src, csr_dst, ptmp, E);
    permute_out_kernel<<<(E + 255) / 256, 256, 0, stream>>>(ptmp, pos_of, d_out, E, flag);
}

// Round 13
// 443.524 us; speedup vs baseline: 1.2133x; 1.0017x over previous
//
#include <hip/hip_runtime.h>
#include <stdint.h>

#define D_IN 512
#define D_HID 256

typedef __attribute__((ext_vector_type(8))) short bf16x8;
typedef __attribute__((ext_vector_type(8))) unsigned short u16x8;
typedef __attribute__((ext_vector_type(4))) float f32x4;

__device__ __forceinline__ float b2f(unsigned short u) {
    union { float f; uint32_t i; } x; x.i = ((uint32_t)u) << 16; return x.f;
}
__device__ __forceinline__ unsigned short f2b(float f) {
    union { float f; uint32_t i; } x; x.f = f;
    uint32_t i = x.i;
    uint32_t r = (i + 0x7FFFu + ((i >> 16) & 1u)) >> 16;
    return (unsigned short)r;
}

// async global->LDS 16B copy; dest is wave-uniform base + lane*16 (HW rule)
__device__ __forceinline__ void async_copy16(const unsigned short* g, unsigned short* lds) {
    __builtin_amdgcn_global_load_lds((const __attribute__((address_space(1))) unsigned int*)g,
                                     (__attribute__((address_space(3))) unsigned int*)lds,
                                     16, 0, 0);
}

// ---------- dtype detector + counts zeroing (fused tail range) ----------
__global__ __launch_bounds__(256) void detect_dtype_kernel(const ushort4* __restrict__ raw,
        int n4, int* __restrict__ flag, int* __restrict__ counts, int N, int dblocks) {
    int b = blockIdx.x;
    if (b >= dblocks) {
        int i = (b - dblocks) * 256 + threadIdx.x;
        if (i < N) counts[i] = 0;
        return;
    }
    int i = b * 256 + threadIdx.x;
    int hit = 0;
    if (i < n4) {
        ushort4 u = raw[i];
        hit = ((((u.x >> 7) & 0xFF) == 0xFF) || (((u.y >> 7) & 0xFF) == 0xFF) ||
               (((u.z >> 7) & 0xFF) == 0xFF) || (((u.w >> 7) & 0xFF) == 0xFF)) ? 1 : 0;
    }
    unsigned long long bl = __ballot(hit);
    if ((threadIdx.x & 63) == 0 && bl != 0ULL) atomicOr(flag, 1);
}

// ---------- W pack body: fragment order ----------
//   Wp[(((kk*2 + h)*16 + c)*64 + lane)*8 + j] = W[kk*64 + h*32 + (lane>>4)*8 + j][c*16 + (lane&15)]
// One wave B-fragment load = 1 KB contiguous (validated r6).
__device__ __forceinline__ void wpack_body(const void* __restrict__ W,
        unsigned short* __restrict__ Wp, int K, bool f32, int t) {
    int total = (K >> 6) * 2 * 16 * 64;
    if (t >= total) return;
    int lane = t & 63;
    int c = (t >> 6) & 15;
    int h = (t >> 10) & 1;
    int kk = t >> 11;
    int n = c * 16 + (lane & 15);
    int k0 = kk * 64 + h * 32 + (lane >> 4) * 8;
    u16x8 o;
#pragma unroll
    for (int j = 0; j < 8; ++j) {
        float v = f32 ? ((const float*)W)[(size_t)(k0 + j) * 256 + n]
                      : b2f(((const unsigned short*)W)[(size_t)(k0 + j) * 256 + n]);
        o[j] = f2b(v);
    }
    *(u16x8*)(Wp + (size_t)t * 8) = o;
}

// ---------- fused independent pre-work: hist (long pole) + wpack1 + wpack2 ----------
// Hist captures the atomicAdd RETURN VALUE as within[e] (rank). The atomic now
// blocks on its return, so each thread runs TWO independent edges (e, e+E/2) to
// overlap the two atomic round-trips.
__global__ __launch_bounds__(256) void pre_fused_kernel(const int* __restrict__ dst,
        int* __restrict__ counts, int* __restrict__ within, int E,
        const void* __restrict__ W1, unsigned short* __restrict__ Wp1,
        const void* __restrict__ W2, unsigned short* __restrict__ Wp2,
        const int* __restrict__ flag, int histBlocks, int wp1Blocks) {
    int b = blockIdx.x;
    if (b < histBlocks) {
        int halfE = (E + 1) >> 1;
        int e = b * 256 + threadIdx.x;
        if (e < halfE) {
            int d1 = dst[e];
            int e2 = e + halfE;
            if (e2 < E) {
                int d2 = dst[e2];
                within[e]  = atomicAdd(&counts[d1], 1);
                within[e2] = atomicAdd(&counts[d2], 1);
            } else {
                within[e] = atomicAdd(&counts[d1], 1);
            }
        }
        return;
    }
    b -= histBlocks;
    bool f32 = (*flag != 0);
    if (b < wp1Blocks) {
        wpack_body(W1, Wp1, D_IN, f32, b * 256 + threadIdx.x);
    } else {
        wpack_body(W2, Wp2, D_HID, f32, (b - wp1Blocks) * 256 + threadIdx.x);
    }
}

// ---------- parallel scan P1/P2/P3 ----------
__global__ __launch_bounds__(256) void partial_sum_kernel(const int* __restrict__ counts,
        int* __restrict__ partial, int n) {
    __shared__ int sh[4];
    int b = blockIdx.x;
    int lane = threadIdx.x & 63, wv = threadIdx.x >> 6;
    int s = 0;
    for (int j = threadIdx.x; j < 1024; j += 256) {
        int i = b * 1024 + j;
        s += (i < n) ? counts[i] : 0;
    }
#pragma unroll
    for (int off = 32; off > 0; off >>= 1) s += __shfl_down(s, off, 64);
    if (lane == 0) sh[wv] = s;
    __syncthreads();
    if (threadIdx.x == 0) partial[b] = sh[0] + sh[1] + sh[2] + sh[3];
}

__global__ void scan_partials_kernel(int* __restrict__ partial, int nb,
                                     int* __restrict__ indptr, int N) {
    int lane = threadIdx.x & 63;
    int orig = (lane < nb) ? partial[lane] : 0;
    int v = orig;
#pragma unroll
    for (int off = 1; off < 64; off <<= 1) {
        int u = __shfl(v, lane - off, 64);
        if (lane >= off) v += u;
    }
    int tot = __shfl(v, nb - 1, 64);
    if (lane < nb) partial[lane] = v - orig;
    if (lane == 0) indptr[N] = tot;
}

__global__ __launch_bounds__(1024) void scan_chunk_kernel(const int* __restrict__ counts,
        const int* __restrict__ partial, int* __restrict__ indptr,
        float* __restrict__ dinv, int n) {
    __shared__ int sh[1024];
    int b = blockIdx.x;
    int i = b * 1024 + threadIdx.x;
    int v = (i < n) ? counts[i] : 0;
    sh[threadIdx.x] = v;
    __syncthreads();
    for (int off = 1; off < 1024; off <<= 1) {
        int t = (threadIdx.x >= off) ? sh[threadIdx.x - off] : 0;
        __syncthreads();
        sh[threadIdx.x] += t;
        __syncthreads();
    }
    if (i < n) {
        int e = partial[b] + sh[threadIdx.x] - v;
        indptr[i] = e;
        dinv[i] = rsqrtf((float)(v + 1));
    }
}

// ---------- MFMA GEMM: C[M,256] = A[M,K] @ W[K,256], fused (FUSE) with:
//   tail range 1: atomic-free CSR fill (pos = indptr[d] + within[e])
//   tail range 2: csr_dst run-fill from indptr (coalesced)
// gemm: 256 thr / 4 waves; tile 64 rows x 256 cols.
//   K=512 + f32 src: reg-staged f32->bf16, BK=64 double-buffered.
//   K=512 + bf16 src: BK=64 double-buffered async_copy16 DMA.
//   K=256 bf16 src: FULL-K staging -- all 4 slices (32 KB LDS) DMA'd up front,
//     ONE vmcnt(0)+barrier, 4 back-to-back compute tiles (no inner drains).
// B from fragment-packed Wp (8 x 1KB coalesced/step).
// LDS per slice: 128B rows, seg rotation (seg+row)&7 (conflict-free).
template<int K, bool MF32, bool FUSE>
__global__ __launch_bounds__(256) void gemm_bf16(const void* __restrict__ Ain,
        const unsigned short* __restrict__ Wp, unsigned short* __restrict__ C, int M,
        const int* __restrict__ flag,
        const int* __restrict__ eidx, const int* __restrict__ within,
        int* __restrict__ csr_src, int* __restrict__ csr_dst, int* __restrict__ pos_of,
        const int* __restrict__ indptr, int E, int sblocks) {
    __shared__ unsigned short As[(K == 256) ? 4 : 2][64 * 64];   // 32 KB / 16 KB
    constexpr int NK = K / 64;
    int bid = blockIdx.x;
    int gblocks = (M + 63) >> 6;
    if (FUSE) {
        if (bid >= gblocks) {
            int tb = bid - gblocks;
            if (tb < sblocks) {
                int e = tb * 256 + (int)threadIdx.x;
                if (e < E) {
                    int d = eidx[(size_t)E + e];
                    int pos = indptr[d] + within[e];     // no atomic
                    csr_src[pos] = eidx[e];              // scattered store (non-blocking)
                    pos_of[e] = pos;                     // coalesced
                }
            } else {
                int v = (tb - sblocks) * 256 + (int)threadIdx.x;
                if (v < M) {
                    int b0 = indptr[v], e0 = indptr[v + 1];
                    for (int p = b0; p < e0; ++p) csr_dst[p] = v;
                }
            }
            return;
        }
    }
    int t = threadIdx.x;
    int lane = t & 63, wv = t >> 6;
    int n0 = lane & 15, grp = lane >> 4;
    int row0 = bid * 64;

    int srow = wv * 16 + (lane >> 3);         // + j*8 added per issue
    int segp = lane & 7;

    f32x4 acc[4][4];
#pragma unroll
    for (int rt = 0; rt < 4; ++rt)
#pragma unroll
        for (int ct = 0; ct < 4; ++ct) acc[rt][ct] = (f32x4){0.f, 0.f, 0.f, 0.f};

    auto compute_tile = [&](int kk, const unsigned short* Abuf) {
        bf16x8 bw[4][2];
#pragma unroll
        for (int ct = 0; ct < 4; ++ct)
#pragma unroll
            for (int h = 0; h < 2; ++h)
                bw[ct][h] = *(const bf16x8*)(Wp +
                    ((size_t)(((kk * 2 + h) * 16) + (wv * 4 + ct)) * 64 + lane) * 8);
#pragma unroll
        for (int rt = 0; rt < 4; ++rt) {
            int r = rt * 16 + n0;
#pragma unroll
            for (int h = 0; h < 2; ++h) {
                int sp = (h * 4 + grp + r) & 7;
                bf16x8 a = *(const bf16x8*)(Abuf + r * 64 + sp * 8);
#pragma unroll
                for (int ct = 0; ct < 4; ++ct)
                    acc[rt][ct] = __builtin_amdgcn_mfma_f32_16x16x32_bf16(a, bw[ct][h],
                                                                          acc[rt][ct], 0, 0, 0);
            }
        }
    };

    bool f32src = MF32 && (*flag != 0);
    if (f32src) {
        const float* A = (const float*)Ain;
        auto stage_f32 = [&](int buf, const float4* pr) {
#pragma unroll
            for (int j = 0; j < 2; ++j) {
                u16x8 o;
#pragma unroll
                for (int q = 0; q < 4; ++q) {
                    o[q]     = f2b(pr[j * 2 + 0][q]);
                    o[q + 4] = f2b(pr[j * 2 + 1][q]);
                }
                *(u16x8*)(&As[buf][0] + wv * 1024 + j * 512 + lane * 8) = o;
            }
        };
        auto load_f32 = [&](int kof, float4* pr) {
#pragma unroll
            for (int j = 0; j < 2; ++j) {
                int row = srow + j * 8;
                int s = (segp - row) & 7;
                const float* g = A + (size_t)min(row0 + row, M - 1) * K + kof + s * 8;
                pr[j * 2 + 0] = *(const float4*)(g);
                pr[j * 2 + 1] = *(const float4*)(g + 4);
            }
        };
        float4 pr[4];
        load_f32(0, pr);
        stage_f32(0, pr);
        for (int kk = 0; kk < NK; ++kk) {
            int cur = kk & 1;
            if (kk + 1 < NK) load_f32((kk + 1) * 64, pr);   // in flight across compute
            asm volatile("s_waitcnt lgkmcnt(0)" ::: "memory");  // my ds_writes done
            __builtin_amdgcn_s_barrier();                       // buf[cur] visible to all
            compute_tile(kk, &As[cur][0]);
            if (kk + 1 < NK) stage_f32(cur ^ 1, pr);
        }
    } else if constexpr (K == 256) {
        // full-K: stage all 4 slices up front (8 DMA issues in flight), one drain
        const unsigned short* A = (const unsigned short*)Ain;
#pragma unroll
        for (int kk = 0; kk < 4; ++kk) {
#pragma unroll
            for (int j = 0; j < 2; ++j) {
                int row = srow + j * 8;
                int s = (segp - row) & 7;
                const unsigned short* g = A + (size_t)min(row0 + row, M - 1) * K
                                           + kk * 64 + s * 8;
                async_copy16(g, &As[kk][0] + wv * 1024 + j * 512);
            }
        }
        asm volatile("s_waitcnt vmcnt(0)" ::: "memory");
        __builtin_amdgcn_s_barrier();
#pragma unroll
        for (int kk = 0; kk < 4; ++kk) compute_tile(kk, &As[kk][0]);
    } else {
        const unsigned short* A = (const unsigned short*)Ain;
#pragma unroll
        for (int j = 0; j < 2; ++j) {
            int row = srow + j * 8;
            int s = (segp - row) & 7;
            const unsigned short* g = A + (size_t)min(row0 + row, M - 1) * K + s * 8;
            async_copy16(g, &As[0][0] + wv * 1024 + j * 512);
        }
        asm volatile("s_waitcnt vmcnt(0)" ::: "memory");
        __builtin_amdgcn_s_barrier();
        for (int kk = 0; kk < NK; ++kk) {
            int cur = kk & 1;
            if (kk + 1 < NK) {
                int kof = (kk + 1) * 64;
#pragma unroll
                for (int j = 0; j < 2; ++j) {
                    int row = srow + j * 8;
                    int s = (segp - row) & 7;
                    const unsigned short* g = A + (size_t)min(row0 + row, M - 1) * K + kof + s * 8;
                    async_copy16(g, &As[cur ^ 1][0] + wv * 1024 + j * 512);
                }
            }
            compute_tile(kk, &As[cur][0]);
            asm volatile("s_waitcnt vmcnt(0)" ::: "memory");
            __builtin_amdgcn_s_barrier();
        }
    }
#pragma unroll
    for (int rt = 0; rt < 4; ++rt) {
#pragma unroll
        for (int ct = 0; ct < 4; ++ct) {
#pragma unroll
            for (int reg = 0; reg < 4; ++reg) {
                int row = row0 + rt * 16 + grp * 4 + reg;
                if (row < M)
                    C[(size_t)row * 256 + (wv * 4 + ct) * 16 + n0] = f2b(acc[rt][ct][reg]);
            }
        }
    }
}

// ---------- GCN aggregation (bf16 h in, bf16 out, f32 accum) ----------
// Two 32-lane halves x mov-free 3-stage rotation; 6 row-loads (3 KB) in flight/wave.
// At the gather request-rate ceiling (~410 MB requested / ~64 us = 6.3 TB/s).
// r9 lesson: do NOT fuse this with LDS-heavy GEMM -- gather throughput scales with
// occupancy (68% here vs 18% fused = 159 us regression).
__global__ __launch_bounds__(256) void aggregate_kernel(const unsigned short* __restrict__ h,
        const int* __restrict__ indptr, const int* __restrict__ csr_src,
        const float* __restrict__ dinv, const void* __restrict__ bias,
        unsigned short* __restrict__ out, int n, int do_relu, const int* __restrict__ flag) {
    int wave = threadIdx.x >> 6;
    int lane = threadIdx.x & 63;
    int half = lane >> 5;
    int hl = lane & 31;
    int v = blockIdx.x * 4 + wave;
    if (v >= n) return;
    int beg = indptr[v];
    int end = indptr[v + 1];
    float dv = dinv[v];

    float acc[8];
    if (half == 0) {
        u16x8 hv = *(const u16x8*)(h + (size_t)v * 256 + hl * 8);
#pragma unroll
        for (int i = 0; i < 8; ++i) acc[i] = dv * b2f(hv[i]);
    } else {
#pragma unroll
        for (int i = 0; i < 8; ++i) acc[i] = 0.f;
    }

    float wA = 0.f, wB = 0.f, wC = 0.f;
    u16x8 rA = (u16x8)0, rB = (u16x8)0, rC = (u16x8)0;
    auto ld = [&](int idx, float& w, u16x8& r) {
        if (idx < end) {
            int s = csr_src[idx];
            w = dinv[s];
            r = *(const u16x8*)(h + (size_t)s * 256 + hl * 8);
        } else {
            w = 0.f;
        }
    };
    int e = beg + half;
    ld(e, wA, rA);
    ld(e + 2, wB, rB);
    ld(e + 4, wC, rC);
    while (e + 4 < end) {
#pragma unroll
        for (int i = 0; i < 8; ++i) acc[i] += wA * b2f(rA[i]);
        ld(e + 6, wA, rA);
#pragma unroll
        for (int i = 0; i < 8; ++i) acc[i] += wB * b2f(rB[i]);
        ld(e + 8, wB, rB);
#pragma unroll
        for (int i = 0; i < 8; ++i) acc[i] += wC * b2f(rC[i]);
        ld(e + 10, wC, rC);
        e += 6;
    }
#pragma unroll
    for (int i = 0; i < 8; ++i)
        acc[i] += wA * b2f(rA[i]) + wB * b2f(rB[i]) + wC * b2f(rC[i]);

#pragma unroll
    for (int i = 0; i < 8; ++i) acc[i] += __shfl_xor(acc[i], 32, 64);

    if (half == 0) {
        float bb[8];
        if (*flag != 0) {
            const float* bp = (const float*)bias + hl * 8;
#pragma unroll
            for (int i = 0; i < 8; ++i) bb[i] = bp[i];
        } else {
            const unsigned short* bp = (const unsigned short*)bias + hl * 8;
#pragma unroll
            for (int i = 0; i < 8; ++i) bb[i] = b2f(bp[i]);
        }
        u16x8 ov;
#pragma unroll
        for (int i = 0; i < 8; ++i) {
            float o = dv * acc[i] + bb[i];
            if (do_relu) o = fmaxf(o, 0.f);
            ov[i] = f2b(o);
        }
        *(u16x8*)(out + (size_t)v * 256 + hl * 8) = ov;
    }
}

// ---------- edge scoring via MFMA: 16 CSR-ordered edges per wave ----------
// CSR order keeps h[dst] cache-resident; h[src] is the irreducible random gather.
// Output to CSR-ordered f32 tmp (coalesced); permute pass restores edge order.
__global__ __launch_bounds__(256) void edge_score_mfma(const unsigned short* __restrict__ h,
        const int* __restrict__ csr_src, const int* __restrict__ csr_dst,
        float* __restrict__ tmp, int E) {
    int lane = threadIdx.x & 63;
    int wv = threadIdx.x >> 6;
    int base = (blockIdx.x * 4 + wv) * 16;
    if (base >= E) return;
    int m = lane & 15, grp = lane >> 4;
    int e = base + m;
    int ec = min(e, E - 1);
    int s = csr_src[ec], d = csr_dst[ec];
    const unsigned short* hs = h + (size_t)s * 256 + grp * 8;
    const unsigned short* hd = h + (size_t)d * 256 + grp * 8;
    f32x4 acc = {0.f, 0.f, 0.f, 0.f};
#pragma unroll
    for (int kk = 0; kk < 8; ++kk) {
        bf16x8 a = *(const bf16x8*)(hs + kk * 32);
        bf16x8 b = *(const bf16x8*)(hd + kk * 32);
        acc = __builtin_amdgcn_mfma_f32_16x16x32_bf16(a, b, acc, 0, 0, 0);
    }
    int reg = m - grp * 4;
    if (reg >= 0 && reg < 4 && e < E) {
        float p = (reg == 0) ? acc[0] : (reg == 1) ? acc[1] : (reg == 2) ? acc[2] : acc[3];
        tmp[e] = 1.f / (1.f + __expf(-p));   // CSR-slot order: coalesced
    }
}

// out[e] = tmp[pos_of[e]] -- L2/L3-resident gather + sequential write.
__global__ __launch_bounds__(256) void permute_out_kernel(const float* __restrict__ tmp,
        const int* __restrict__ pos_of, void* __restrict__ out, int E,
        const int* __restrict__ flag) {
    int e = blockIdx.x * blockDim.x + threadIdx.x;
    if (e >= E) return;
    float p = tmp[pos_of[e]];
    if (*flag != 0)
        ((float*)out)[e] = p;
    else
        ((unsigned short*)out)[e] = f2b(p);
}

extern "C" void kernel_launch(void* const* d_in, const int* in_sizes, int n_in,
                              void* d_out, int out_size, void* d_ws, size_t ws_size,
                              hipStream_t stream) {
    const void* x  = d_in[0];
    const int* edge_index = (const int*)d_in[1];
    const void* W1 = d_in[2];
    const void* b1 = d_in[3];
    const void* W2 = d_in[4];
    const void* b2 = d_in[5];

    const int N = in_sizes[0] / D_IN;   // 50000
    const int E = in_sizes[1] / 2;      // 800000
    const int* dst = edge_index + E;

    char* ws = (char*)d_ws;
    size_t off = 0;
    auto alloc = [&](size_t bytes) {
        char* p = ws + off;
        off = (off + bytes + 255) & ~(size_t)255;
        return p;
    };
    int* flag     = (int*)alloc(256);
    float* dinv   = (float*)alloc((size_t)N * 4);
    int* counts   = (int*)alloc((size_t)N * 4);
    int* indptr   = (int*)alloc((size_t)(N + 1) * 4);
    int* partial  = (int*)alloc(64 * 4);
    int* within   = (int*)alloc((size_t)E * 4);
    int* csr_src  = (int*)alloc((size_t)E * 4);
    int* csr_dst  = (int*)alloc((size_t)E * 4);
    int* pos_of   = (int*)alloc((size_t)E * 4);
    float* ptmp   = (float*)alloc((size_t)E * 4);
    unsigned short* Wp1 = (unsigned short*)alloc((size_t)D_IN * 256 * 2);
    unsigned short* Wp2 = (unsigned short*)alloc((size_t)D_HID * 256 * 2);
    unsigned short* hA  = (unsigned short*)alloc((size_t)N * 256 * 2);    // 25.6 MB
    unsigned short* hB  = (unsigned short*)alloc((size_t)N * 256 * 2);    // 25.6 MB

    const int nb = (N + 1023) / 1024;   // 49 <= 64
    const int halfE = (E + 1) / 2;
    const int histBlocks = (halfE + 255) / 256;     // 1563
    const int sblocks = (E + 255) / 256;            // 3125
    const int fblocks = (N + 255) / 256;            // 196
    const int wp1Blocks = (D_IN * 32) / 256;        // 64
    const int wp2Blocks = (D_HID * 32) / 256;       // 32
    const int ggrid = (N + 63) / 64;                // 782
    const int dblocks = 64;

    hipMemsetAsync(flag, 0, 4, stream);
    detect_dtype_kernel<<<dblocks + fblocks, 256, 0, stream>>>(
        (const ushort4*)x, 16384, flag, counts, N, dblocks);
    pre_fused_kernel<<<histBlocks + wp1Blocks + wp2Blocks, 256, 0, stream>>>(
        dst, counts, within, E, W1, Wp1, W2, Wp2, flag, histBlocks, wp1Blocks);
    partial_sum_kernel<<<nb, 256, 0, stream>>>(counts, partial, N);
    scan_partials_kernel<<<1, 64, 0, stream>>>(partial, nb, indptr, N);
    scan_chunk_kernel<<<nb, 1024, 0, stream>>>(counts, partial, indptr, dinv, N);

    // gemm1 (blocks first) + atomic-free CSR fill + csr_dst run-fill, one launch
    gemm_bf16<D_IN, true, true><<<ggrid + sblocks + fblocks, 256, 0, stream>>>(
        x, Wp1, hA, N, flag, edge_index, within, csr_src, csr_dst, pos_of, indptr, E, sblocks);
    aggregate_kernel<<<(N + 3) / 4, 256, 0, stream>>>(hA, indptr, csr_src, dinv, b1, hB, N, 1, flag);
    gemm_bf16<D_HID, false, false><<<ggrid, 256, 0, stream>>>(
        hB, Wp2, hA, N, flag, nullptr, nullptr, nullptr, nullptr, nullptr, nullptr, 0, 0);
    aggregate_kernel<<<(N + 3) / 4, 256, 0, stream>>>(hA, indptr, csr_src, dinv, b2, hB, N, 0, flag);
    edge_score_mfma<<<(E + 63) / 64, 256, 0, stream>>>(hB, csr_src, csr_dst, ptmp, E);
    permute_out_kernel<<<(E + 255) / 256, 256, 0, stream>>>(ptmp, pos_of, d_out, E, flag);
}